// Round 8
// baseline (263.661 us; speedup 1.0000x reference)
//
#include <hip/hip_runtime.h>
#include <cstdint>

#define NT 8192
#define DD 1024
#define NE 8
#define BK 32
#define KHALF 512
#define NKIT2 (KHALF / BK)     // 16 iters per half-pipeline
#define MAXTILE 72

typedef __attribute__((ext_vector_type(8))) _Float16 half8;
typedef __attribute__((ext_vector_type(4))) float f32x4;

__device__ __forceinline__ unsigned short f2h_bits(float f) {
  _Float16 h = (_Float16)f;
  return __builtin_bit_cast(unsigned short, h);
}

// async global->LDS, 16B per lane. LDS dest must be wave-uniform base + lane*16;
// the GLOBAL address is an ordinary per-lane VGPR address (indirection is fine).
#define GLDS16(gp, lp) __builtin_amdgcn_global_load_lds( \
  (__attribute__((address_space(1))) void*)(uintptr_t)(gp), \
  (__attribute__((address_space(3))) void*)(uintptr_t)(lp), 16, 0, 0)

// s_waitcnt imm (gfx9): vmcnt[3:0]|[15:14], expcnt[6:4], lgkmcnt[11:8]; 0xF70|N = vmcnt(N) only
#define WAITCNT_VM4  0xF74
#define WAITCNT_VM0  0xF70

// ---------------- weight cast+transpose: fp32 [e][k][n] -> fp16 [e][n][k] ----------------
__global__ __launch_bounds__(256) void wcast_kernel(
    const float* __restrict__ W1, const float* __restrict__ W2,
    _Float16* __restrict__ W1t, _Float16* __restrict__ W2t) {
  __shared__ float tile[64][65];
  const int z = blockIdx.z;                // 0..15: [0,8)=W1, [8,16)=W2
  const float* W = (z < 8 ? W1 : W2) + (size_t)(z & 7) * (DD * DD);
  _Float16* Wt   = (z < 8 ? W1t : W2t) + (size_t)(z & 7) * (DD * DD);
  const int k0 = blockIdx.x * 64, n0 = blockIdx.y * 64;
  const int tid = threadIdx.x;
#pragma unroll
  for (int it = 0; it < 4; ++it) {
    int idx = it * 256 + tid;              // 0..1023
    int r = idx >> 4;                      // k-row 0..63
    int q = idx & 15;                      // float4 col
    float4 v = *(const float4*)(W + (size_t)(k0 + r) * DD + n0 + q * 4);
    tile[r][q * 4 + 0] = v.x; tile[r][q * 4 + 1] = v.y;
    tile[r][q * 4 + 2] = v.z; tile[r][q * 4 + 3] = v.w;
  }
  __syncthreads();
#pragma unroll
  for (int it = 0; it < 4; ++it) {
    int idx = it * 256 + tid;
    int n = idx >> 4;                      // out row (n) 0..63
    int q = idx & 15;                      // k 4-chunk
    ushort4 o;
    o.x = f2h_bits(tile[q * 4 + 0][n]);
    o.y = f2h_bits(tile[q * 4 + 1][n]);
    o.z = f2h_bits(tile[q * 4 + 2][n]);
    o.w = f2h_bits(tile[q * 4 + 3][n]);
    *(ushort4*)(Wt + (size_t)(n0 + n) * DD + k0 + q * 4) = o;
  }
}

// ---------------- gating: Wg staged to LDS (e-major); also emits xh = fp16(x) ----------------
__global__ __launch_bounds__(256) void gate_kernel(
    const float* __restrict__ x, const float* __restrict__ Wg, const float* __restrict__ bg,
    int* __restrict__ assign, float* __restrict__ wgt, _Float16* __restrict__ xh) {
  __shared__ float WgL[NE * DD];           // 32 KB, e-major: WgL[e*DD + k]
  const int tid = threadIdx.x;
#pragma unroll
  for (int it = 0; it < 8; ++it) {
    int idx = it * 256 + tid;              // float4 index 0..2047
    float4 v = ((const float4*)Wg)[idx];
    int k = idx >> 1;
    int e0 = (idx & 1) * 4;
    WgL[(e0 + 0) * DD + k] = v.x;
    WgL[(e0 + 1) * DD + k] = v.y;
    WgL[(e0 + 2) * DD + k] = v.z;
    WgL[(e0 + 3) * DD + k] = v.w;
  }
  __syncthreads();
  const int lane = tid & 63, w = tid >> 6;
#pragma unroll
  for (int s = 0; s < 2; ++s) {
    const int t = blockIdx.x * 8 + w * 2 + s;
    const float4* xr = (const float4*)(x + (size_t)t * DD);
    float4 xv[4];
#pragma unroll
    for (int c = 0; c < 4; ++c) xv[c] = xr[lane + 64 * c];
    ushort4* xo = (ushort4*)(xh + (size_t)t * DD);
#pragma unroll
    for (int c = 0; c < 4; ++c) {
      union { ushort4 u; _Float16 h[4]; } cv;
      cv.h[0] = (_Float16)xv[c].x; cv.h[1] = (_Float16)xv[c].y;
      cv.h[2] = (_Float16)xv[c].z; cv.h[3] = (_Float16)xv[c].w;
      xo[lane + 64 * c] = cv.u;
    }
    float p[NE];
#pragma unroll
    for (int e = 0; e < NE; ++e) {
      float acc = 0.f;
#pragma unroll
      for (int c = 0; c < 4; ++c) {
        float4 wv = *(const float4*)&WgL[e * DD + 4 * lane + 256 * c];
        acc += xv[c].x * wv.x + xv[c].y * wv.y + xv[c].z * wv.z + xv[c].w * wv.w;
      }
      p[e] = acc;
    }
#pragma unroll
    for (int e = 0; e < NE; ++e) {
      float v = p[e];
      for (int off = 32; off > 0; off >>= 1) v += __shfl_down(v, off, 64);
      p[e] = v;
    }
    if (lane == 0) {
      float l[NE];
#pragma unroll
      for (int e = 0; e < NE; ++e) l[e] = p[e] + bg[e];
      int a = 0; float best = l[0];
#pragma unroll
      for (int e = 1; e < NE; ++e) if (l[e] > best) { best = l[e]; a = e; }
      float sum = 0.f;
#pragma unroll
      for (int e = 0; e < NE; ++e) sum += expf(l[e] - best);
      assign[t] = a;
      wgt[t] = 1.0f / sum;
    }
  }
}

// ---------------- sort: deterministic counting sort + tile plan, single block ----------------
__global__ __launch_bounds__(1024) void sort_kernel(
    const int* __restrict__ assign, int* __restrict__ rowtok, int* __restrict__ plan) {
  __shared__ int sc[NE * 1024];            // 32 KB, e-major
  const int tid = threadIdx.x;
  int a[8];
  int c[NE];
#pragma unroll
  for (int e = 0; e < NE; ++e) c[e] = 0;
#pragma unroll
  for (int j = 0; j < 8; ++j) { a[j] = assign[tid * 8 + j]; ++c[a[j]]; }
#pragma unroll
  for (int e = 0; e < NE; ++e) sc[e * 1024 + tid] = c[e];
  __syncthreads();
  for (int d = 1; d < 1024; d <<= 1) {
    int add[NE];
    if (tid >= d) {
#pragma unroll
      for (int e = 0; e < NE; ++e) add[e] = sc[e * 1024 + tid - d];
    }
    __syncthreads();
    if (tid >= d) {
#pragma unroll
      for (int e = 0; e < NE; ++e) sc[e * 1024 + tid] += add[e];
    }
    __syncthreads();
  }
  int tot[NE], incl[NE];
#pragma unroll
  for (int e = 0; e < NE; ++e) { tot[e] = sc[e * 1024 + 1023]; incl[e] = sc[e * 1024 + tid]; }
  int offs[NE];
  {
    int s = 0;
#pragma unroll
    for (int e = 0; e < NE; ++e) { offs[e] = s; s += tot[e]; }
  }
  int run[NE];
#pragma unroll
  for (int e = 0; e < NE; ++e) run[e] = offs[e] + incl[e] - c[e];
#pragma unroll
  for (int j = 0; j < 8; ++j) { int e = a[j]; rowtok[run[e]++] = tid * 8 + j; }
  if (tid == 0) {
    int nt = 0;
    for (int e = 0; e < NE; ++e) {
      int cc = tot[e], st = offs[e];
      int t_cnt = (cc + 127) >> 7;
      for (int t = 0; t < t_cnt; ++t) {
        plan[1 + nt] = e;
        plan[1 + MAXTILE + nt] = st + t * 128;
        plan[1 + 2 * MAXTILE + nt] = st + cc;
        ++nt;
      }
    }
    plan[0] = nt;
  }
}

// ---------------- grouped GEMM: 128x128 tile, 512 threads, intra-block split-K ----------------
// Two independent 4-wave pipelines per block: pipe p (waves 4p..4p+3) computes k in
// [p*512, p*512+512) with its own 2-buffer BK=32 staged LDS region (4 x 16 KB = 64 KB).
// Doubles concurrent staging streams per CU without extra global traffic; half-accs are
// combined through LDS (reusing the staging buffers) before the epilogue.
// MODE 0: H[p] = gelu_exact(xh[rowtok[p]] @ W1t^T + b1)  -> fp16
// MODE 1: out[rowtok[p]] = (H[p] @ W2t^T + b2) * wgt      -> fp32 scatter
template <int MODE>
__global__ __launch_bounds__(512) void gemm_kernel(
    const _Float16* __restrict__ A,
    const _Float16* __restrict__ Wt,
    const float* __restrict__ bias,
    const int* __restrict__ plan,
    _Float16* __restrict__ Hout,
    float* __restrict__ Fout,
    const int* __restrict__ rowtok,
    const float* __restrict__ wgt) {
  const int wrk = blockIdx.x;
  const int tile = wrk >> 3;
  if (tile >= plan[0]) return;
  const int e = plan[1 + tile];
  const int m0 = plan[1 + MAXTILE + tile];
  const int seg_end = plan[1 + 2 * MAXTILE + tile];
  const int n0 = (wrk & 7) * 128;

  const int tid = threadIdx.x;
  const int pipe = tid >> 8;           // 0 or 1: which k-half
  const int ptid = tid & 255;
  const int lane = tid & 63;
  const int w = tid >> 6;
  const int pw = w & 3;                // wave index within pipe
  const int wm = pw >> 1, wn = pw & 1;
  const int quad = lane >> 4;
  const int r15 = lane & 15;
  const int kbase = pipe * KHALF;

  // LDS: [A: pipe0 buf0|buf1, pipe1 buf0|buf1][B: same] = 8 x 8 KB = 64 KB
  __shared__ alignas(16) char lds[65536];
  char* ldsA = lds;                    // 32 KB
  char* ldsB = lds + 32768;            // 32 KB

  // staging: per thread 2 A-slots + 2 B-slots within its pipe; slot s in [0,512):
  // row = s>>2, stored chunk sc = s&3, logical chunk c = sc ^ ((row>>1)&3)
  const _Float16* We = Wt + (size_t)e * DD * DD;
  const _Float16* gAp[2];
  const _Float16* gBp[2];
  int ldso[2];
#pragma unroll
  for (int i = 0; i < 2; ++i) {
    int slot = i * 256 + ptid;
    int row = slot >> 2;
    int c = (slot & 3) ^ ((row >> 1) & 3);
    int rg = m0 + row; if (rg > NT - 1) rg = NT - 1;
    int arow = (MODE == 0) ? rowtok[rg] : rg;
    gAp[i] = A + (size_t)arow * DD + kbase + c * 8;
    gBp[i] = We + (size_t)(n0 + row) * DD + kbase + c * 8;
    ldso[i] = slot * 16;               // byte offset within one 8 KB buffer
  }

  // fragment read offsets (half8 units within one buffer): row*4 + (quad ^ ((row>>1)&3))
  int aoff[4], boff[4];
#pragma unroll
  for (int i = 0; i < 4; ++i) {
    int m = wm * 64 + i * 16 + r15;
    aoff[i] = m * 4 + (quad ^ ((m >> 1) & 3));
    int n = wn * 64 + i * 16 + r15;
    boff[i] = n * 4 + (quad ^ ((n >> 1) & 3));
  }

  f32x4 acc[4][4];
  f32x4 zero4 = {0.f, 0.f, 0.f, 0.f};
#pragma unroll
  for (int mi = 0; mi < 4; ++mi)
#pragma unroll
    for (int ni = 0; ni < 4; ++ni) acc[mi][ni] = zero4;

#define STAGE(KT, BUF) do {                                          \
    const int rb_ = ((pipe << 1) | (BUF)) << 13;                     \
    char* la_ = ldsA + rb_;                                          \
    char* lb_ = ldsB + rb_;                                          \
    const int ko_ = (KT) * BK;                                       \
    _Pragma("unroll") for (int i_ = 0; i_ < 2; ++i_)                 \
      GLDS16(gAp[i_] + ko_, la_ + ldso[i_]);                         \
    _Pragma("unroll") for (int i_ = 0; i_ < 2; ++i_)                 \
      GLDS16(gBp[i_] + ko_, lb_ + ldso[i_]);                         \
  } while (0)

  STAGE(0, 0);                         // prologue prefetch into buffer 0

#pragma unroll 1
  for (int kt = 0; kt < NKIT2; ++kt) {
    const int buf = kt & 1;
    __builtin_amdgcn_s_barrier();      // all waves done reading buf^1 (iter kt-1)
    __asm__ volatile("" ::: "memory");
    if (kt + 1 < NKIT2) {
      STAGE(kt + 1, buf ^ 1);          // async prefetch; stays in flight across barrier
      __builtin_amdgcn_s_waitcnt(WAITCNT_VM4);   // wait only my 4 loads for buf(kt)
    } else {
      __builtin_amdgcn_s_waitcnt(WAITCNT_VM0);
    }
    __builtin_amdgcn_s_barrier();      // buffer kt visible to all waves of both pipes
    __asm__ volatile("" ::: "memory");
    const half8* AsV = (const half8*)(ldsA + (((pipe << 1) | buf) << 13));
    const half8* BsV = (const half8*)(ldsB + (((pipe << 1) | buf) << 13));
    half8 a[4], b[4];
#pragma unroll
    for (int i = 0; i < 4; ++i) a[i] = AsV[aoff[i]];
#pragma unroll
    for (int i = 0; i < 4; ++i) b[i] = BsV[boff[i]];
#pragma unroll
    for (int mi = 0; mi < 4; ++mi)
#pragma unroll
      for (int ni = 0; ni < 4; ++ni)
        acc[mi][ni] = __builtin_amdgcn_mfma_f32_16x16x32_f16(a[mi], b[ni], acc[mi][ni], 0, 0, 0);
  }
#undef STAGE

  // ---- combine the two k-halves through LDS (reuse staging buffers: 128*128 f32 = 64 KB)
  __syncthreads();                     // all LDS buffer reads done, accs final
  float* comb = (float*)lds;
  // element (row,col) -> LDS addr row*128 + (col ^ (quad<<4)); quad = (row>>2)&3 is a
  // pure function of row, so writer (pipe 1) and reader (pipe 0) agree. XOR kills the
  // 4-way quad bank alias (2-way max = free).
  if (pipe == 1) {
#pragma unroll
    for (int mi = 0; mi < 4; ++mi) {
      int rowb = wm * 64 + mi * 16 + quad * 4;
#pragma unroll
      for (int ni = 0; ni < 4; ++ni) {
        int col = wn * 64 + ni * 16 + r15;
        int cx = col ^ (quad << 4);
#pragma unroll
        for (int r = 0; r < 4; ++r) comb[(rowb + r) * 128 + cx] = acc[mi][ni][r];
      }
    }
  }
  __syncthreads();
  if (pipe == 1) return;

  const float* bptr = bias + (size_t)e * DD;
#pragma unroll
  for (int mi = 0; mi < 4; ++mi) {
    int rowb = m0 + wm * 64 + mi * 16 + quad * 4;
    int rowl = wm * 64 + mi * 16 + quad * 4;
#pragma unroll
    for (int r = 0; r < 4; ++r) {
      int gpos = rowb + r;
      if (gpos < seg_end) {
        if (MODE == 0) {
#pragma unroll
          for (int ni = 0; ni < 4; ++ni) {
            int col = wn * 64 + ni * 16 + r15;
            int n = n0 + col;
            float val = acc[mi][ni][r] + comb[(rowl + r) * 128 + (col ^ (quad << 4))] + bptr[n];
            val = 0.5f * val * (1.0f + erff(val * 0.70710678118654752f));
            Hout[(size_t)gpos * DD + n] = (_Float16)val;
          }
        } else {
          int tok = rowtok[gpos];
          float wv = wgt[tok];
          float* orow = Fout + (size_t)tok * DD;
#pragma unroll
          for (int ni = 0; ni < 4; ++ni) {
            int col = wn * 64 + ni * 16 + r15;
            int n = n0 + col;
            float val = acc[mi][ni][r] + comb[(rowl + r) * 128 + (col ^ (quad << 4))] + bptr[n];
            orow[n] = val * wv;
          }
        }
      }
    }
  }
}

extern "C" void kernel_launch(void* const* d_in, const int* in_sizes, int n_in,
                              void* d_out, int out_size, void* d_ws, size_t ws_size,
                              hipStream_t stream) {
  const float* x  = (const float*)d_in[0];
  const float* Wg = (const float*)d_in[1];
  const float* bg = (const float*)d_in[2];
  const float* W1 = (const float*)d_in[3];
  const float* b1 = (const float*)d_in[4];
  const float* W2 = (const float*)d_in[5];
  const float* b2 = (const float*)d_in[6];
  float* out = (float*)d_out;

  char* ws = (char*)d_ws;
  const size_t MB16 = (size_t)1 << 24;
  _Float16* W1t = (_Float16*)(ws + 0 * MB16);
  _Float16* W2t = (_Float16*)(ws + 1 * MB16);
  _Float16* xh  = (_Float16*)(ws + 2 * MB16);
  _Float16* H   = (_Float16*)(ws + 3 * MB16);
  int*   assign = (int*)(ws + 4 * MB16);
  int*   rowtok = assign + NT;
  float* wgt    = (float*)(rowtok + NT);
  int*   plan   = (int*)(wgt + NT);    // [1 + 3*MAXTILE]

  wcast_kernel<<<dim3(16, 16, 16), 256, 0, stream>>>(W1, W2, W1t, W2t);
  gate_kernel<<<NT / 8, 256, 0, stream>>>(x, Wg, bg, assign, wgt, xh);
  sort_kernel<<<1, 1024, 0, stream>>>(assign, rowtok, plan);
  gemm_kernel<0><<<MAXTILE * 8, 512, 0, stream>>>(xh, W1t, b1, plan, H, nullptr, rowtok, nullptr);
  gemm_kernel<1><<<MAXTILE * 8, 512, 0, stream>>>(H, W2t, b2, plan, nullptr, out, rowtok, wgt);
}

// Round 9
// 254.927 us; speedup vs baseline: 1.0343x; 1.0343x over previous
//
#include <hip/hip_runtime.h>
#include <cstdint>

#define NT 8192
#define DD 1024
#define NE 8
#define BK 32
#define NKIT (DD / BK)
#define TM 64                  // m-tile
#define MAXTILE 136            // sum ceil(c/64) <= 8192/64 + 8

typedef __attribute__((ext_vector_type(8))) _Float16 half8;
typedef __attribute__((ext_vector_type(4))) float f32x4;

__device__ __forceinline__ unsigned short f2h_bits(float f) {
  _Float16 h = (_Float16)f;
  return __builtin_bit_cast(unsigned short, h);
}

// async global->LDS, 16B per lane. LDS dest must be wave-uniform base + lane*16;
// the GLOBAL address is an ordinary per-lane VGPR address (indirection is fine).
#define GLDS16(gp, lp) __builtin_amdgcn_global_load_lds( \
  (__attribute__((address_space(1))) void*)(uintptr_t)(gp), \
  (__attribute__((address_space(3))) void*)(uintptr_t)(lp), 16, 0, 0)

// s_waitcnt imm (gfx9): vmcnt[3:0]|[15:14], expcnt[6:4], lgkmcnt[11:8]; 0xF70|N = vmcnt(N) only
#define WAITCNT_VM3  0xF73
#define WAITCNT_VM0  0xF70

// ---------------- weight cast+transpose: fp32 [e][k][n] -> fp16 [e][n][k] ----------------
__global__ __launch_bounds__(256) void wcast_kernel(
    const float* __restrict__ W1, const float* __restrict__ W2,
    _Float16* __restrict__ W1t, _Float16* __restrict__ W2t) {
  __shared__ float tile[64][65];
  const int z = blockIdx.z;                // 0..15: [0,8)=W1, [8,16)=W2
  const float* W = (z < 8 ? W1 : W2) + (size_t)(z & 7) * (DD * DD);
  _Float16* Wt   = (z < 8 ? W1t : W2t) + (size_t)(z & 7) * (DD * DD);
  const int k0 = blockIdx.x * 64, n0 = blockIdx.y * 64;
  const int tid = threadIdx.x;
#pragma unroll
  for (int it = 0; it < 4; ++it) {
    int idx = it * 256 + tid;              // 0..1023
    int r = idx >> 4;                      // k-row 0..63
    int q = idx & 15;                      // float4 col
    float4 v = *(const float4*)(W + (size_t)(k0 + r) * DD + n0 + q * 4);
    tile[r][q * 4 + 0] = v.x; tile[r][q * 4 + 1] = v.y;
    tile[r][q * 4 + 2] = v.z; tile[r][q * 4 + 3] = v.w;
  }
  __syncthreads();
#pragma unroll
  for (int it = 0; it < 4; ++it) {
    int idx = it * 256 + tid;
    int n = idx >> 4;                      // out row (n) 0..63
    int q = idx & 15;                      // k 4-chunk
    ushort4 o;
    o.x = f2h_bits(tile[q * 4 + 0][n]);
    o.y = f2h_bits(tile[q * 4 + 1][n]);
    o.z = f2h_bits(tile[q * 4 + 2][n]);
    o.w = f2h_bits(tile[q * 4 + 3][n]);
    *(ushort4*)(Wt + (size_t)(n0 + n) * DD + k0 + q * 4) = o;
  }
}

// ---------------- gating: Wg staged to LDS (e-major); also emits xh = fp16(x) ----------------
__global__ __launch_bounds__(256) void gate_kernel(
    const float* __restrict__ x, const float* __restrict__ Wg, const float* __restrict__ bg,
    int* __restrict__ assign, float* __restrict__ wgt, _Float16* __restrict__ xh) {
  __shared__ float WgL[NE * DD];           // 32 KB, e-major: WgL[e*DD + k]
  const int tid = threadIdx.x;
#pragma unroll
  for (int it = 0; it < 8; ++it) {
    int idx = it * 256 + tid;              // float4 index 0..2047
    float4 v = ((const float4*)Wg)[idx];
    int k = idx >> 1;
    int e0 = (idx & 1) * 4;
    WgL[(e0 + 0) * DD + k] = v.x;
    WgL[(e0 + 1) * DD + k] = v.y;
    WgL[(e0 + 2) * DD + k] = v.z;
    WgL[(e0 + 3) * DD + k] = v.w;
  }
  __syncthreads();
  const int lane = tid & 63, w = tid >> 6;
#pragma unroll
  for (int s = 0; s < 2; ++s) {
    const int t = blockIdx.x * 8 + w * 2 + s;
    const float4* xr = (const float4*)(x + (size_t)t * DD);
    float4 xv[4];
#pragma unroll
    for (int c = 0; c < 4; ++c) xv[c] = xr[lane + 64 * c];
    ushort4* xo = (ushort4*)(xh + (size_t)t * DD);
#pragma unroll
    for (int c = 0; c < 4; ++c) {
      union { ushort4 u; _Float16 h[4]; } cv;
      cv.h[0] = (_Float16)xv[c].x; cv.h[1] = (_Float16)xv[c].y;
      cv.h[2] = (_Float16)xv[c].z; cv.h[3] = (_Float16)xv[c].w;
      xo[lane + 64 * c] = cv.u;
    }
    float p[NE];
#pragma unroll
    for (int e = 0; e < NE; ++e) {
      float acc = 0.f;
#pragma unroll
      for (int c = 0; c < 4; ++c) {
        float4 wv = *(const float4*)&WgL[e * DD + 4 * lane + 256 * c];
        acc += xv[c].x * wv.x + xv[c].y * wv.y + xv[c].z * wv.z + xv[c].w * wv.w;
      }
      p[e] = acc;
    }
#pragma unroll
    for (int e = 0; e < NE; ++e) {
      float v = p[e];
      for (int off = 32; off > 0; off >>= 1) v += __shfl_down(v, off, 64);
      p[e] = v;
    }
    if (lane == 0) {
      float l[NE];
#pragma unroll
      for (int e = 0; e < NE; ++e) l[e] = p[e] + bg[e];
      int a = 0; float best = l[0];
#pragma unroll
      for (int e = 1; e < NE; ++e) if (l[e] > best) { best = l[e]; a = e; }
      float sum = 0.f;
#pragma unroll
      for (int e = 0; e < NE; ++e) sum += expf(l[e] - best);
      assign[t] = a;
      wgt[t] = 1.0f / sum;
    }
  }
}

// ---------------- sort: deterministic counting sort + tile plan (64-row tiles) ----------------
__global__ __launch_bounds__(1024) void sort_kernel(
    const int* __restrict__ assign, int* __restrict__ rowtok, int* __restrict__ plan) {
  __shared__ int sc[NE * 1024];            // 32 KB, e-major
  const int tid = threadIdx.x;
  int a[8];
  int c[NE];
#pragma unroll
  for (int e = 0; e < NE; ++e) c[e] = 0;
#pragma unroll
  for (int j = 0; j < 8; ++j) { a[j] = assign[tid * 8 + j]; ++c[a[j]]; }
#pragma unroll
  for (int e = 0; e < NE; ++e) sc[e * 1024 + tid] = c[e];
  __syncthreads();
  for (int d = 1; d < 1024; d <<= 1) {
    int add[NE];
    if (tid >= d) {
#pragma unroll
      for (int e = 0; e < NE; ++e) add[e] = sc[e * 1024 + tid - d];
    }
    __syncthreads();
    if (tid >= d) {
#pragma unroll
      for (int e = 0; e < NE; ++e) sc[e * 1024 + tid] += add[e];
    }
    __syncthreads();
  }
  int tot[NE], incl[NE];
#pragma unroll
  for (int e = 0; e < NE; ++e) { tot[e] = sc[e * 1024 + 1023]; incl[e] = sc[e * 1024 + tid]; }
  int offs[NE];
  {
    int s = 0;
#pragma unroll
    for (int e = 0; e < NE; ++e) { offs[e] = s; s += tot[e]; }
  }
  int run[NE];
#pragma unroll
  for (int e = 0; e < NE; ++e) run[e] = offs[e] + incl[e] - c[e];
#pragma unroll
  for (int j = 0; j < 8; ++j) { int e = a[j]; rowtok[run[e]++] = tid * 8 + j; }
  if (tid == 0) {
    int nt = 0;
    for (int e = 0; e < NE; ++e) {
      int cc = tot[e], st = offs[e];
      int t_cnt = (cc + TM - 1) / TM;
      for (int t = 0; t < t_cnt; ++t) {
        plan[1 + nt] = e;
        plan[1 + MAXTILE + nt] = st + t * TM;
        plan[1 + 2 * MAXTILE + nt] = st + cc;
        ++nt;
      }
    }
    plan[0] = nt;
  }
}

// ---------------- grouped GEMM: 64x128 tile, BK=32, dbuf, fine-vmcnt pipeline ----------------
// Halved m-tile -> ~2x blocks (~4.5/CU): per-CU staging streams was the only lever that
// ever moved throughput (R5-R8 intra-block experiments all neutral). LDS 24 KB/block.
// Each of 4 waves: 64m x 32n (acc 4x2). Per thread per iter: 1 A + 2 B GLDS16.
// MODE 0: H[p] = gelu_exact(xh[rowtok[p]] @ W1t^T + b1)  -> fp16
// MODE 1: out[rowtok[p]] = (H[p] @ W2t^T + b2) * wgt      -> fp32 scatter
template <int MODE>
__global__ __launch_bounds__(256) void gemm_kernel(
    const _Float16* __restrict__ A,
    const _Float16* __restrict__ Wt,
    const float* __restrict__ bias,
    const int* __restrict__ plan,
    _Float16* __restrict__ Hout,
    float* __restrict__ Fout,
    const int* __restrict__ rowtok,
    const float* __restrict__ wgt) {
  const int wrk = blockIdx.x;
  const int tile = wrk >> 3;
  if (tile >= plan[0]) return;
  const int e = plan[1 + tile];
  const int m0 = plan[1 + MAXTILE + tile];
  const int seg_end = plan[1 + 2 * MAXTILE + tile];
  const int n0 = (wrk & 7) * 128;

  const int tid = threadIdx.x;
  const int lane = tid & 63;
  const int wn = tid >> 6;             // wave 0..3 -> n strip of 32
  const int quad = lane >> 4;
  const int r15 = lane & 15;

  // LDS: As 2 x 4 KB, Bs 2 x 8 KB = 24 KB
  __shared__ alignas(16) char lds[24576];
  char* ldsA = lds;                    // [buf][64 rows x 4 chunks x 16B]
  char* ldsB = lds + 8192;             // [buf][128 rows x 4 chunks x 16B]

  // staging addresses. slot -> row = slot>>2, stored chunk sc = slot&3,
  // logical chunk c = sc ^ ((row>>1)&3)  (chunk = 8 halves = 16B)
  const _Float16* We = Wt + (size_t)e * DD * DD;
  const _Float16* gAp;                 // 1 per thread (slot = tid, 64 rows)
  const _Float16* gBp[2];              // 2 per thread (slots tid, tid+256; 128 rows)
  int ldsoA, ldsoB[2];
  {
    int slot = tid;
    int row = slot >> 2;
    int c = (slot & 3) ^ ((row >> 1) & 3);
    int rg = m0 + row; if (rg > NT - 1) rg = NT - 1;
    int arow = (MODE == 0) ? rowtok[rg] : rg;
    gAp = A + (size_t)arow * DD + c * 8;
    ldsoA = slot * 16;
  }
#pragma unroll
  for (int i = 0; i < 2; ++i) {
    int slot = i * 256 + tid;
    int row = slot >> 2;
    int c = (slot & 3) ^ ((row >> 1) & 3);
    gBp[i] = We + (size_t)(n0 + row) * DD + c * 8;
    ldsoB[i] = slot * 16;
  }

  // fragment read offsets (half8 units): row*4 + (quad ^ ((row>>1)&3))
  int aoff[4], boff[2];
#pragma unroll
  for (int i = 0; i < 4; ++i) {
    int m = i * 16 + r15;
    aoff[i] = m * 4 + (quad ^ ((m >> 1) & 3));
  }
#pragma unroll
  for (int i = 0; i < 2; ++i) {
    int n = wn * 32 + i * 16 + r15;
    boff[i] = n * 4 + (quad ^ ((n >> 1) & 3));
  }

  f32x4 acc[4][2];
  f32x4 zero4 = {0.f, 0.f, 0.f, 0.f};
#pragma unroll
  for (int mi = 0; mi < 4; ++mi)
#pragma unroll
    for (int ni = 0; ni < 2; ++ni) acc[mi][ni] = zero4;

#define STAGE(KT, BUF) do {                                          \
    const int ko_ = (KT) * BK;                                       \
    char* la_ = ldsA + ((BUF) << 12);                                \
    char* lb_ = ldsB + ((BUF) << 13);                                \
    GLDS16(gAp + ko_, la_ + ldsoA);                                  \
    GLDS16(gBp[0] + ko_, lb_ + ldsoB[0]);                            \
    GLDS16(gBp[1] + ko_, lb_ + ldsoB[1]);                            \
  } while (0)

  STAGE(0, 0);                         // prologue prefetch into buffer 0

#pragma unroll 1
  for (int kt = 0; kt < NKIT; ++kt) {
    const int buf = kt & 1;
    __builtin_amdgcn_s_barrier();      // all waves done reading buf^1 (iter kt-1)
    __asm__ volatile("" ::: "memory");
    if (kt + 1 < NKIT) {
      STAGE(kt + 1, buf ^ 1);          // async prefetch; stays in flight across barrier
      __builtin_amdgcn_s_waitcnt(WAITCNT_VM3);   // wait only buf(kt)'s 3 loads
    } else {
      __builtin_amdgcn_s_waitcnt(WAITCNT_VM0);
    }
    __builtin_amdgcn_s_barrier();      // buffer kt visible to all waves
    __asm__ volatile("" ::: "memory");
    const half8* AsV = (const half8*)(ldsA + (buf << 12));
    const half8* BsV = (const half8*)(ldsB + (buf << 13));
    half8 a[4], b[2];
#pragma unroll
    for (int i = 0; i < 4; ++i) a[i] = AsV[aoff[i]];
#pragma unroll
    for (int i = 0; i < 2; ++i) b[i] = BsV[boff[i]];
#pragma unroll
    for (int mi = 0; mi < 4; ++mi)
#pragma unroll
      for (int ni = 0; ni < 2; ++ni)
        acc[mi][ni] = __builtin_amdgcn_mfma_f32_16x16x32_f16(a[mi], b[ni], acc[mi][ni], 0, 0, 0);
  }
#undef STAGE

  // epilogue. C/D layout: col = lane&15, row = quad*4 + reg
  const float* bptr = bias + (size_t)e * DD;
#pragma unroll
  for (int mi = 0; mi < 4; ++mi) {
    int rowb = m0 + mi * 16 + quad * 4;
#pragma unroll
    for (int r = 0; r < 4; ++r) {
      int gpos = rowb + r;
      if (gpos < seg_end) {
        if (MODE == 0) {
#pragma unroll
          for (int ni = 0; ni < 2; ++ni) {
            int n = n0 + wn * 32 + ni * 16 + r15;
            float val = acc[mi][ni][r] + bptr[n];
            val = 0.5f * val * (1.0f + erff(val * 0.70710678118654752f));
            Hout[(size_t)gpos * DD + n] = (_Float16)val;
          }
        } else {
          int tok = rowtok[gpos];
          float wv = wgt[tok];
          float* orow = Fout + (size_t)tok * DD;
#pragma unroll
          for (int ni = 0; ni < 2; ++ni) {
            int n = n0 + wn * 32 + ni * 16 + r15;
            orow[n] = (acc[mi][ni][r] + bptr[n]) * wv;
          }
        }
      }
    }
  }
}

extern "C" void kernel_launch(void* const* d_in, const int* in_sizes, int n_in,
                              void* d_out, int out_size, void* d_ws, size_t ws_size,
                              hipStream_t stream) {
  const float* x  = (const float*)d_in[0];
  const float* Wg = (const float*)d_in[1];
  const float* bg = (const float*)d_in[2];
  const float* W1 = (const float*)d_in[3];
  const float* b1 = (const float*)d_in[4];
  const float* W2 = (const float*)d_in[5];
  const float* b2 = (const float*)d_in[6];
  float* out = (float*)d_out;

  char* ws = (char*)d_ws;
  const size_t MB16 = (size_t)1 << 24;
  _Float16* W1t = (_Float16*)(ws + 0 * MB16);
  _Float16* W2t = (_Float16*)(ws + 1 * MB16);
  _Float16* xh  = (_Float16*)(ws + 2 * MB16);
  _Float16* H   = (_Float16*)(ws + 3 * MB16);
  int*   assign = (int*)(ws + 4 * MB16);
  int*   rowtok = assign + NT;
  float* wgt    = (float*)(rowtok + NT);
  int*   plan   = (int*)(wgt + NT);    // [1 + 3*MAXTILE]

  wcast_kernel<<<dim3(16, 16, 16), 256, 0, stream>>>(W1, W2, W1t, W2t);
  gate_kernel<<<NT / 8, 256, 0, stream>>>(x, Wg, bg, assign, wgt, xh);
  sort_kernel<<<1, 1024, 0, stream>>>(assign, rowtok, plan);
  gemm_kernel<0><<<MAXTILE * 8, 256, 0, stream>>>(xh, W1t, b1, plan, H, nullptr, rowtok, nullptr);
  gemm_kernel<1><<<MAXTILE * 8, 256, 0, stream>>>(H, W2t, b2, plan, nullptr, out, rowtok, wgt);
}